// Round 3
// baseline (376.686 us; speedup 1.0000x reference)
//
#include <hip/hip_runtime.h>
#include <math.h>

#define D 128
#define H 128
#define BQ 1024
#define M 512
#define NNODES 500000
#define K_MAX 8
#define SHORT 16
#define NB 512        // sort buckets (node >> 10 -> 0..488)
#define NEDGE (BQ * M)
#define NTILE (NEDGE / 64)

typedef __attribute__((ext_vector_type(8))) short bf16x8;
typedef __attribute__((ext_vector_type(4))) float f32x4;
typedef __attribute__((ext_vector_type(4))) float f32x4v;

// RNE fp32->bf16, packed pair
static __device__ __forceinline__ unsigned pack2bf(float a, float b) {
    unsigned ua = __float_as_uint(a);
    unsigned ub = __float_as_uint(b);
    ua = ua + 0x7fffu + ((ua >> 16) & 1u);
    ub = ub + 0x7fffu + ((ub >> 16) & 1u);
    return (ua >> 16) | (ub & 0xffff0000u);
}

// ---------------------------------------------------------------------------
// Phase 0: W1 bottom half -> bf16, h-major, linear image of swizzled LDS tile
// ---------------------------------------------------------------------------
__global__ void wconv_kernel(const float* __restrict__ W1,
                             unsigned short* __restrict__ wTswz) {
    const int idx = blockIdx.x * 256 + threadIdx.x;  // 0..16383
    const int h = idx >> 7;
    const int inner = (idx & 127) * 2;
    const int k = (inner ^ ((h & 7) << 4)) >> 1;
    const float v = W1[(long)(D + k) * H + h];
    wTswz[idx] = (unsigned short)pack2bf(v, 0.f);
}

// ---------------------------------------------------------------------------
// Phase 1: qh[b][h] = b1[h] + embed[query[b]] . W1top
// ---------------------------------------------------------------------------
__global__ void qproj_kernel(const float* __restrict__ embed,
                             const float* __restrict__ W1,
                             const float* __restrict__ b1,
                             const int* __restrict__ query_idx,
                             float* __restrict__ qh) {
    __shared__ float qrow[D];
    const int b = blockIdx.x;
    const int t = threadIdx.x;
    const long qi = query_idx[b];
    qrow[t] = embed[qi * D + t];
    __syncthreads();
    float acc = b1[t];
#pragma unroll 8
    for (int d = 0; d < D; ++d)
        acc = fmaf(qrow[d], W1[d * H + t], acc);
    qh[b * H + t] = acc;
}

// ---------------------------------------------------------------------------
// Sort phase A: bucket histogram (LDS-local, then global atomics)
// 256 blocks x 256 threads, 8 edges/thread
// ---------------------------------------------------------------------------
__global__ __launch_bounds__(256)
void hist_kernel(const int* __restrict__ cand_idx, int* __restrict__ hist) {
    __shared__ int lh[NB];
    const int t = threadIdx.x;
    lh[t] = 0; lh[t + 256] = 0;
    __syncthreads();
    const int base = blockIdx.x * 2048;
#pragma unroll
    for (int j = 0; j < 8; ++j) {
        const int node = cand_idx[base + j * 256 + t];
        atomicAdd(&lh[node >> 10], 1);
    }
    __syncthreads();
    if (lh[t]) atomicAdd(&hist[t], lh[t]);
    if (lh[t + 256]) atomicAdd(&hist[t + 256], lh[t + 256]);
}

// ---------------------------------------------------------------------------
// Sort phase B: exclusive scan of hist -> offs (1 block, 512 threads)
// ---------------------------------------------------------------------------
__global__ __launch_bounds__(NB)
void scan_kernel(const int* __restrict__ hist, int* __restrict__ offs) {
    __shared__ int s[NB];
    const int t = threadIdx.x;
    const int h0 = hist[t];
    s[t] = h0;
    __syncthreads();
    for (int off = 1; off < NB; off <<= 1) {
        int v = 0;
        if (t >= off) v = s[t - off];
        __syncthreads();
        s[t] += v;
        __syncthreads();
    }
    offs[t] = s[t] - h0;
}

// ---------------------------------------------------------------------------
// Sort phase C: scatter {node, edge-enc} pairs into bucket order.
// Within-bucket order is nondeterministic (atomic), but every output value
// is a pure per-edge function -> outputs are bit-identical regardless.
// ---------------------------------------------------------------------------
__global__ __launch_bounds__(256)
void scatter_kernel(const int* __restrict__ cand_idx, int* __restrict__ offs,
                    int2* __restrict__ sorted) {
    const int tid = blockIdx.x * 256 + threadIdx.x;  // 0..NEDGE-1 (= b*M+m)
    const int node = cand_idx[tid];
    const int pos = atomicAdd(&offs[node >> 10], 1);
    sorted[pos] = make_int2(node, tid);
}

// ---------------------------------------------------------------------------
// Phase 2 (sorted): approximate scores via bf16 MFMA over sorted edge list.
// 64 edges x 128 h per block, K=128; XOR-swizzled LDS; XCD-aware tile swizzle.
// ---------------------------------------------------------------------------
__global__ __launch_bounds__(256)
void score_sorted_kernel(const float* __restrict__ embed,
                         const unsigned short* __restrict__ wTswz,
                         const float* __restrict__ W2,
                         const float* __restrict__ b2,
                         const int2* __restrict__ sorted,
                         const float* __restrict__ qh,
                         float* __restrict__ scores) {
    __shared__ __align__(16) char smem[16384 + 32768];
    char* As = smem;
    char* Bs = smem + 16384;

    // bijective XCD swizzle: consecutive tiles (shared node window) -> same XCD
    const int tile = (blockIdx.x & 7) * (NTILE / 8) + (blockIdx.x >> 3);
    const int i0 = tile * 64;
    const int t = threadIdx.x;

    // ---- stage A: gather 64 sorted candidate rows, cvt->bf16, swizzled
    {
        const int e = t >> 2;
        const int q = t & 3;
        const long node = sorted[i0 + e].x;
        const float4* rowp = (const float4*)(embed + node * D);
        const int sw = (e & 7) << 4;
#pragma unroll
        for (int i = 0; i < 8; ++i) {
            const int c4 = i * 4 + q;
            const float4 v = rowp[c4];
            uint2 p;
            p.x = pack2bf(v.x, v.y);
            p.y = pack2bf(v.z, v.w);
            *(uint2*)(As + (e << 8) + ((c4 * 8) ^ sw)) = p;
        }
    }
    // ---- stage B: linear copy of pre-swizzled bf16 W1bot
    {
#pragma unroll
        for (int i = 0; i < 8; ++i) {
            const int c = i * 256 + t;
            const uint4 v = ((const uint4*)wTswz)[c];
            *(uint4*)(Bs + (size_t)c * 16) = v;
        }
    }
    __syncthreads();

    const int lane = t & 63;
    const int w    = t >> 6;
    const int g    = lane >> 4;
    const int c    = lane & 15;
    const int sw   = (c & 7) << 4;

    f32x4 acc[8];
#pragma unroll
    for (int cb = 0; cb < 8; ++cb) acc[cb] = (f32x4){0.f, 0.f, 0.f, 0.f};

    const int arow = (w * 16 + c) << 8;
#pragma unroll
    for (int ks = 0; ks < 4; ++ks) {
        const int koff = (ks * 64 + g * 16) ^ sw;
        const bf16x8 a = *(const bf16x8*)(As + arow + koff);
#pragma unroll
        for (int cb = 0; cb < 8; ++cb) {
            const bf16x8 bv = *(const bf16x8*)(Bs + ((cb * 16 + c) << 8) + koff);
            acc[cb] = __builtin_amdgcn_mfma_f32_16x16x32_bf16(a, bv, acc[cb], 0, 0, 0);
        }
    }

    // ---- epilogue: per-edge b (sorted order). D layout: col(h)=lane&15,
    // row(edge)=(lane>>4)*4+reg.
    int enc[4];
    const float* qrow[4];
#pragma unroll
    for (int r = 0; r < 4; ++r) {
        enc[r] = sorted[i0 + w * 16 + g * 4 + r].y;      // b*M+m
        qrow[r] = qh + (long)(enc[r] >> 9) * H;          // M=512
    }
    float s0 = 0.f, s1 = 0.f, s2 = 0.f, s3 = 0.f;
#pragma unroll
    for (int cb = 0; cb < 8; ++cb) {
        const int hq = cb * 16 + c;
        const float w2 = W2[hq];
        s0 = fmaf(fmaxf(qrow[0][hq] + acc[cb][0], 0.f), w2, s0);
        s1 = fmaf(fmaxf(qrow[1][hq] + acc[cb][1], 0.f), w2, s1);
        s2 = fmaf(fmaxf(qrow[2][hq] + acc[cb][2], 0.f), w2, s2);
        s3 = fmaf(fmaxf(qrow[3][hq] + acc[cb][3], 0.f), w2, s3);
    }
#pragma unroll
    for (int off = 1; off <= 8; off <<= 1) {
        s0 += __shfl_xor(s0, off);
        s1 += __shfl_xor(s1, off);
        s2 += __shfl_xor(s2, off);
        s3 += __shfl_xor(s3, off);
    }
    if (c == 0) {
        const float b2v = b2[0];
        scores[enc[0]] = s0 + b2v;
        scores[enc[1]] = s1 + b2v;
        scores[enc[2]] = s2 + b2v;
        scores[enc[3]] = s3 + b2v;
    }
}

// ---------------------------------------------------------------------------
// Phase 2 fallback (unsorted, uniform b per tile) — used if ws too small.
// ---------------------------------------------------------------------------
__global__ __launch_bounds__(256)
void score_unsorted_kernel(const float* __restrict__ embed,
                           const unsigned short* __restrict__ wTswz,
                           const float* __restrict__ W2,
                           const float* __restrict__ b2,
                           const int* __restrict__ cand_idx,
                           const float* __restrict__ qh,
                           float* __restrict__ scores) {
    __shared__ __align__(16) char smem[16384 + 32768];
    char* As = smem;
    char* Bs = smem + 16384;

    const int bid = blockIdx.x;
    const int b   = bid >> 3;
    const int m0  = (bid & 7) * 64;
    const int t   = threadIdx.x;

    {
        const int e = t >> 2;
        const int q = t & 3;
        const long node = cand_idx[b * M + m0 + e];
        const float4* rowp = (const float4*)(embed + node * D);
        const int sw = (e & 7) << 4;
#pragma unroll
        for (int i = 0; i < 8; ++i) {
            const int c4 = i * 4 + q;
            const float4 v = rowp[c4];
            uint2 p;
            p.x = pack2bf(v.x, v.y);
            p.y = pack2bf(v.z, v.w);
            *(uint2*)(As + (e << 8) + ((c4 * 8) ^ sw)) = p;
        }
    }
    {
#pragma unroll
        for (int i = 0; i < 8; ++i) {
            const int c = i * 256 + t;
            const uint4 v = ((const uint4*)wTswz)[c];
            *(uint4*)(Bs + (size_t)c * 16) = v;
        }
    }
    __syncthreads();

    const int lane = t & 63;
    const int w    = t >> 6;
    const int g    = lane >> 4;
    const int c    = lane & 15;
    const int sw   = (c & 7) << 4;

    f32x4 acc[8];
#pragma unroll
    for (int cb = 0; cb < 8; ++cb) acc[cb] = (f32x4){0.f, 0.f, 0.f, 0.f};

    const int arow = (w * 16 + c) << 8;
#pragma unroll
    for (int ks = 0; ks < 4; ++ks) {
        const int koff = (ks * 64 + g * 16) ^ sw;
        const bf16x8 a = *(const bf16x8*)(As + arow + koff);
#pragma unroll
        for (int cb = 0; cb < 8; ++cb) {
            const bf16x8 bv = *(const bf16x8*)(Bs + ((cb * 16 + c) << 8) + koff);
            acc[cb] = __builtin_amdgcn_mfma_f32_16x16x32_bf16(a, bv, acc[cb], 0, 0, 0);
        }
    }

    float s0 = 0.f, s1 = 0.f, s2 = 0.f, s3 = 0.f;
#pragma unroll
    for (int cb = 0; cb < 8; ++cb) {
        const int hq = cb * 16 + c;
        const float qv = qh[b * H + hq];
        const float w2 = W2[hq];
        s0 = fmaf(fmaxf(qv + acc[cb][0], 0.f), w2, s0);
        s1 = fmaf(fmaxf(qv + acc[cb][1], 0.f), w2, s1);
        s2 = fmaf(fmaxf(qv + acc[cb][2], 0.f), w2, s2);
        s3 = fmaf(fmaxf(qv + acc[cb][3], 0.f), w2, s3);
    }
#pragma unroll
    for (int off = 1; off <= 8; off <<= 1) {
        s0 += __shfl_xor(s0, off);
        s1 += __shfl_xor(s1, off);
        s2 += __shfl_xor(s2, off);
        s3 += __shfl_xor(s3, off);
    }
    if (c == 0) {
        const float b2v = b2[0];
        float* out = scores + b * M + m0 + w * 16 + g * 4;
        out[0] = s0 + b2v;
        out[1] = s1 + b2v;
        out[2] = s2 + b2v;
        out[3] = s3 + b2v;
    }
}

// ---------------------------------------------------------------------------
// Phase 3a: approximate top-16 shortlist positions per row (1 wave/row)
// ---------------------------------------------------------------------------
__global__ void topk16_kernel(const float* __restrict__ scores,
                              int* __restrict__ shortpos) {
    const int b = blockIdx.x;
    const int lane = threadIdx.x;
    const float* row = scores + b * M;
    float v[8];
    {
        const float4 x0 = ((const float4*)row)[lane * 2];
        const float4 x1 = ((const float4*)row)[lane * 2 + 1];
        v[0] = x0.x; v[1] = x0.y; v[2] = x0.z; v[3] = x0.w;
        v[4] = x1.x; v[5] = x1.y; v[6] = x1.z; v[7] = x1.w;
    }
    for (int kk = 0; kk < SHORT; ++kk) {
        float bv = v[0];
        int bi = lane * 8;
#pragma unroll
        for (int j = 1; j < 8; ++j)
            if (v[j] > bv) { bv = v[j]; bi = lane * 8 + j; }
#pragma unroll
        for (int off = 32; off >= 1; off >>= 1) {
            const float ov = __shfl_xor(bv, off);
            const int   oi = __shfl_xor(bi, off);
            if (ov > bv || (ov == bv && oi < bi)) { bv = ov; bi = oi; }
        }
        if (lane == 0) shortpos[b * SHORT + kk] = bi;
        if ((bi >> 3) == lane) v[bi & 7] = -3.402823466e38f;
    }
}

// ---------------------------------------------------------------------------
// Phase 3b: exact fp32 rescore of shortlist, top-k with lax.top_k semantics
// ---------------------------------------------------------------------------
__global__ __launch_bounds__(128)
void refine_kernel(const float* __restrict__ embed,
                   const float* __restrict__ W1,
                   const float* __restrict__ W2,
                   const float* __restrict__ qh,
                   const int* __restrict__ cand_idx,
                   const int* __restrict__ shortpos,
                   const int* __restrict__ topk_ptr,
                   int* __restrict__ top_nodes) {
    __shared__ float crows[SHORT][D];
    __shared__ float red[SHORT][D];
    __shared__ int spos[SHORT];
    const int b = blockIdx.x;
    const int t = threadIdx.x;

    if (t < SHORT) spos[t] = shortpos[b * SHORT + t];
    __syncthreads();
    {
        const int cc = t >> 3;
        const int d0 = (t & 7) * 16;
        const long node = cand_idx[b * M + spos[cc]];
        const float4* rp = (const float4*)(embed + node * D);
        float4* wp = (float4*)&crows[cc][d0];
#pragma unroll
        for (int j = 0; j < 4; ++j) wp[j] = rp[d0 / 4 + j];
    }
    __syncthreads();

    float acc[SHORT];
#pragma unroll
    for (int cc = 0; cc < SHORT; ++cc) acc[cc] = 0.f;
    const float* W1bot = W1 + (long)D * H;
    for (int d = 0; d < D; ++d) {
        const float w1v = W1bot[d * H + t];
#pragma unroll
        for (int cc = 0; cc < SHORT; ++cc)
            acc[cc] = fmaf(crows[cc][d], w1v, acc[cc]);
    }
    const float qv = qh[b * H + t];
    const float w2 = W2[t];
#pragma unroll
    for (int cc = 0; cc < SHORT; ++cc)
        red[cc][t] = fmaxf(qv + acc[cc], 0.f) * w2;
    __syncthreads();

    if (t < 64) {
#pragma unroll
        for (int cc = 0; cc < SHORT; ++cc) {
            float v = red[cc][t] + red[cc][t + 64];
#pragma unroll
            for (int off = 32; off >= 1; off >>= 1) v += __shfl_xor(v, off);
            if (t == 0) red[cc][0] = v;
        }
    }
    __syncthreads();

    if (t == 0) {
        int k = *topk_ptr;
        if (k > K_MAX) k = K_MAX;
        unsigned used = 0;
        for (int kk = 0; kk < K_MAX; ++kk) {
            if (kk < k) {
                int best = -1, bpos = 0x7fffffff;
                float bv = 0.f;
                for (int cc = 0; cc < SHORT; ++cc) {
                    if (used & (1u << cc)) continue;
                    const float v = red[cc][0];
                    const int p = spos[cc];
                    if (best < 0 || v > bv || (v == bv && p < bpos)) {
                        best = cc; bv = v; bpos = p;
                    }
                }
                used |= 1u << best;
                top_nodes[b * K_MAX + kk] = cand_idx[b * M + bpos];
            } else {
                top_nodes[b * K_MAX + kk] = -1;
            }
        }
    }
}

// ---------------------------------------------------------------------------
// Phase 4a: masked_feat = node_feat, nontemporal (preserve embed in L2/L3)
// ---------------------------------------------------------------------------
__global__ void copy_kernel(const f32x4v* __restrict__ src,
                            f32x4v* __restrict__ dst, long n4) {
    long i = (long)blockIdx.x * blockDim.x + threadIdx.x;
    const long stride = (long)gridDim.x * blockDim.x;
    for (; i < n4; i += stride) {
        const f32x4v v = __builtin_nontemporal_load(&src[i]);
        __builtin_nontemporal_store(v, &dst[i]);
    }
}

// ---------------------------------------------------------------------------
// Phase 4b: zero the selected rows
// ---------------------------------------------------------------------------
__global__ void zero_rows_kernel(const int* __restrict__ top_nodes,
                                 float* __restrict__ masked) {
    const int node = top_nodes[blockIdx.x];
    if (node < 0) return;
    masked[(long)node * D + threadIdx.x] = 0.f;
}

// ---------------------------------------------------------------------------
extern "C" void kernel_launch(void* const* d_in, const int* in_sizes, int n_in,
                              void* d_out, int out_size, void* d_ws, size_t ws_size,
                              hipStream_t stream) {
    const float* embed     = (const float*)d_in[0];
    const float* node_feat = (const float*)d_in[1];
    const float* W1        = (const float*)d_in[2];
    const float* b1        = (const float*)d_in[3];
    const float* W2        = (const float*)d_in[4];
    const float* b2        = (const float*)d_in[5];
    const int*   query_idx = (const int*)d_in[6];
    const int*   cand_idx  = (const int*)d_in[7];
    const int*   topk_ptr  = (const int*)d_in[8];

    float* scores = (float*)d_out;                 // B*M
    float* masked = (float*)d_out + (long)BQ * M;  // N*D

    // ws layout
    char* p = (char*)d_ws;
    float*          qh        = (float*)p;            p += (long)BQ * H * 4;     // 512 KB
    int*            shortpos  = (int*)p;              p += (long)BQ * SHORT * 4; // 64 KB
    int*            top_nodes = (int*)p;              p += (long)BQ * K_MAX * 4; // 32 KB
    unsigned short* wTswz     = (unsigned short*)p;   p += (long)H * D * 2;      // 32 KB
    int*            hist      = (int*)p;              p += NB * 4;
    int*            offs      = (int*)p;              p += NB * 4;
    int2*           sorted    = (int2*)p;             p += (long)NEDGE * 8;      // 4 MB
    const size_t need = (size_t)(p - (char*)d_ws);

    wconv_kernel<<<(H * D) / 256, 256, 0, stream>>>(W1, wTswz);
    qproj_kernel<<<BQ, H, 0, stream>>>(embed, W1, b1, query_idx, qh);

    if (ws_size >= need) {
        hipMemsetAsync(hist, 0, NB * sizeof(int), stream);
        hist_kernel<<<NEDGE / 2048, 256, 0, stream>>>(cand_idx, hist);
        scan_kernel<<<1, NB, 0, stream>>>(hist, offs);
        scatter_kernel<<<NEDGE / 256, 256, 0, stream>>>(cand_idx, offs, sorted);
        score_sorted_kernel<<<NTILE, 256, 0, stream>>>(embed, wTswz, W2, b2,
                                                       sorted, qh, scores);
    } else {
        score_unsorted_kernel<<<NTILE, 256, 0, stream>>>(embed, wTswz, W2, b2,
                                                         cand_idx, qh, scores);
    }

    topk16_kernel<<<BQ, 64, 0, stream>>>(scores, shortpos);
    refine_kernel<<<BQ, 128, 0, stream>>>(embed, W1, W2, qh, cand_idx,
                                          shortpos, topk_ptr, top_nodes);

    const long n4 = (long)NNODES * D / 4;
    copy_kernel<<<2048, 256, 0, stream>>>((const f32x4v*)node_feat,
                                          (f32x4v*)masked, n4);
    zero_rows_kernel<<<BQ * K_MAX, D, 0, stream>>>(top_nodes, masked);
}

// Round 5
// 205.624 us; speedup vs baseline: 1.8319x; 1.8319x over previous
//
#include <hip/hip_runtime.h>
#include <math.h>

#define D 128
#define H 128
#define BQ 1024
#define M 512
#define NNODES 500000
#define K_MAX 8
#define SHORT 16
#define NTILE (BQ * M / 64)        // 8192 score tiles
#define NCOPY 2048                 // copy blocks
#define COPY_N4 ((long)NNODES * D / 4)

typedef __attribute__((ext_vector_type(8))) short bf16x8;
typedef __attribute__((ext_vector_type(4))) float f32x4;

// RNE fp32->bf16, packed pair
static __device__ __forceinline__ unsigned pack2bf(float a, float b) {
    unsigned ua = __float_as_uint(a);
    unsigned ub = __float_as_uint(b);
    ua = ua + 0x7fffu + ((ua >> 16) & 1u);
    ub = ub + 0x7fffu + ((ub >> 16) & 1u);
    return (ua >> 16) | (ub & 0xffff0000u);
}

// ---------------------------------------------------------------------------
// Phase 0: W1 bottom half -> bf16, h-major, linear image of swizzled LDS tile
// ---------------------------------------------------------------------------
__global__ void wconv_kernel(const float* __restrict__ W1,
                             unsigned short* __restrict__ wTswz) {
    const int idx = blockIdx.x * 256 + threadIdx.x;  // 0..16383
    const int h = idx >> 7;
    const int inner = (idx & 127) * 2;
    const int k = (inner ^ ((h & 7) << 4)) >> 1;
    const float v = W1[(long)(D + k) * H + h];
    wTswz[idx] = (unsigned short)pack2bf(v, 0.f);
}

// ---------------------------------------------------------------------------
// Phase 1: qh[b][h] = b1[h] + embed[query[b]] . W1top   (fp32)
// ---------------------------------------------------------------------------
__global__ void qproj_kernel(const float* __restrict__ embed,
                             const float* __restrict__ W1,
                             const float* __restrict__ b1,
                             const int* __restrict__ query_idx,
                             float* __restrict__ qh) {
    __shared__ float qrow[D];
    const int b = blockIdx.x;
    const int t = threadIdx.x;
    const long qi = query_idx[b];
    qrow[t] = embed[qi * D + t];
    __syncthreads();
    float acc = b1[t];
#pragma unroll 8
    for (int d = 0; d < D; ++d)
        acc = fmaf(qrow[d], W1[d * H + t], acc);
    qh[b * H + t] = acc;
}

// ---------------------------------------------------------------------------
// Phase 2 (FUSED): score tiles + node_feat copy in one heterogeneous launch.
// blockIdx % 5 == 0  -> copy block   (2048 of 10240)
// else               -> score tile   (8192 of 10240)
// Interleaving keeps both kinds co-resident: copy saturates HBM while score
// blocks sit in gather latency; MFMA/VALU pipes stay on the score side.
// ---------------------------------------------------------------------------
__global__ __launch_bounds__(256)
void fused_kernel(const float* __restrict__ embed,
                  const unsigned short* __restrict__ wTswz,
                  const float* __restrict__ W2,
                  const float* __restrict__ b2,
                  const int* __restrict__ cand_idx,
                  const float* __restrict__ qh,
                  float* __restrict__ scores,
                  const f32x4* __restrict__ nf_src,
                  f32x4* __restrict__ nf_dst) {
    __shared__ __align__(16) char smem[16384 + 32768];
    const int bid = blockIdx.x;
    const int t   = threadIdx.x;

    if (bid % 5 == 0) {
        // ---------------- copy block: nontemporal streaming ----------------
        const int cb = bid / 5;                       // 0..NCOPY-1
        long i = (long)cb * 256 + t;
        const long stride = (long)NCOPY * 256;
        for (; i < COPY_N4; i += stride) {
            const f32x4 v = __builtin_nontemporal_load(&nf_src[i]);
            __builtin_nontemporal_store(v, &nf_dst[i]);
        }
        return;
    }

    // ------------------- score tile: 64 edges x 128 h ----------------------
    char* As = smem;            // [e][k] bf16, XOR-swizzled
    char* Bs = smem + 16384;    // [h][k] bf16, pre-swizzled image

    const int tile = bid - bid / 5 - 1;   // 0..NTILE-1
    const int b   = tile >> 3;
    const int m0  = (tile & 7) * 64;

    {   // stage A: gather 64 candidate rows, cvt->bf16, swizzled write
        const int e = t >> 2;
        const int q = t & 3;
        const long node = cand_idx[b * M + m0 + e];
        const float* rowp = embed + node * D;
        const int sw = (e & 7) << 4;
#pragma unroll
        for (int i = 0; i < 8; ++i) {
            const int c4 = i * 4 + q;
            const f32x4 v = *(const f32x4*)(rowp + c4 * 4);
            uint2 p;
            p.x = pack2bf(v.x, v.y);
            p.y = pack2bf(v.z, v.w);
            *(uint2*)(As + (e << 8) + ((c4 * 8) ^ sw)) = p;
        }
    }
    {   // stage B: linear copy of pre-swizzled bf16 W1bot
#pragma unroll
        for (int i = 0; i < 8; ++i) {
            const int c = i * 256 + t;
            const uint4 v = ((const uint4*)wTswz)[c];
            *(uint4*)(Bs + (size_t)c * 16) = v;
        }
    }
    __syncthreads();

    const int lane = t & 63;
    const int w    = t >> 6;       // wave id = edge band
    const int g    = lane >> 4;    // k-group
    const int c    = lane & 15;    // row/col within band
    const int sw   = (c & 7) << 4;

    f32x4 acc[8];
#pragma unroll
    for (int cb2 = 0; cb2 < 8; ++cb2) acc[cb2] = (f32x4){0.f, 0.f, 0.f, 0.f};

    const int arow = (w * 16 + c) << 8;
#pragma unroll
    for (int ks = 0; ks < 4; ++ks) {
        const int koff = (ks * 64 + g * 16) ^ sw;
        const bf16x8 a = *(const bf16x8*)(As + arow + koff);
#pragma unroll
        for (int cb2 = 0; cb2 < 8; ++cb2) {
            const bf16x8 bv = *(const bf16x8*)(Bs + ((cb2 * 16 + c) << 8) + koff);
            acc[cb2] = __builtin_amdgcn_mfma_f32_16x16x32_bf16(a, bv, acc[cb2], 0, 0, 0);
        }
    }

    // epilogue: relu(qh + acc) . W2 ; butterfly-reduce over 16 lanes (h)
    float s0 = 0.f, s1 = 0.f, s2 = 0.f, s3 = 0.f;
#pragma unroll
    for (int cb2 = 0; cb2 < 8; ++cb2) {
        const int hq = cb2 * 16 + c;
        const float qv = qh[b * H + hq];
        const float w2 = W2[hq];
        s0 = fmaf(fmaxf(qv + acc[cb2][0], 0.f), w2, s0);
        s1 = fmaf(fmaxf(qv + acc[cb2][1], 0.f), w2, s1);
        s2 = fmaf(fmaxf(qv + acc[cb2][2], 0.f), w2, s2);
        s3 = fmaf(fmaxf(qv + acc[cb2][3], 0.f), w2, s3);
    }
#pragma unroll
    for (int off = 1; off <= 8; off <<= 1) {
        s0 += __shfl_xor(s0, off);
        s1 += __shfl_xor(s1, off);
        s2 += __shfl_xor(s2, off);
        s3 += __shfl_xor(s3, off);
    }
    if (c == 0) {
        const float b2v = b2[0];
        float* out = scores + b * M + m0 + w * 16 + g * 4;
        out[0] = s0 + b2v;
        out[1] = s1 + b2v;
        out[2] = s2 + b2v;
        out[3] = s3 + b2v;
    }
}

// ---------------------------------------------------------------------------
// Phase 3a: approximate top-16 shortlist positions per row (1 wave/row)
// ---------------------------------------------------------------------------
__global__ void topk16_kernel(const float* __restrict__ scores,
                              int* __restrict__ shortpos) {
    const int b = blockIdx.x;
    const int lane = threadIdx.x;
    const float* row = scores + b * M;
    float v[8];
    {
        const float4 x0 = ((const float4*)row)[lane * 2];
        const float4 x1 = ((const float4*)row)[lane * 2 + 1];
        v[0] = x0.x; v[1] = x0.y; v[2] = x0.z; v[3] = x0.w;
        v[4] = x1.x; v[5] = x1.y; v[6] = x1.z; v[7] = x1.w;
    }
    for (int kk = 0; kk < SHORT; ++kk) {
        float bv = v[0];
        int bi = lane * 8;
#pragma unroll
        for (int j = 1; j < 8; ++j)
            if (v[j] > bv) { bv = v[j]; bi = lane * 8 + j; }
#pragma unroll
        for (int off = 32; off >= 1; off >>= 1) {
            const float ov = __shfl_xor(bv, off);
            const int   oi = __shfl_xor(bi, off);
            if (ov > bv || (ov == bv && oi < bi)) { bv = ov; bi = oi; }
        }
        if (lane == 0) shortpos[b * SHORT + kk] = bi;
        if ((bi >> 3) == lane) v[bi & 7] = -3.402823466e38f;
    }
}

// ---------------------------------------------------------------------------
// Phase 3b: exact fp32 rescore of shortlist, top-k with lax.top_k semantics
// ---------------------------------------------------------------------------
__global__ __launch_bounds__(128)
void refine_kernel(const float* __restrict__ embed,
                   const float* __restrict__ W1,
                   const float* __restrict__ W2,
                   const float* __restrict__ qh,
                   const int* __restrict__ cand_idx,
                   const int* __restrict__ shortpos,
                   const int* __restrict__ topk_ptr,
                   int* __restrict__ top_nodes) {
    __shared__ float crows[SHORT][D];
    __shared__ float red[SHORT][D];
    __shared__ int spos[SHORT];
    const int b = blockIdx.x;
    const int t = threadIdx.x;

    if (t < SHORT) spos[t] = shortpos[b * SHORT + t];
    __syncthreads();
    {
        const int cc = t >> 3;
        const int d0 = (t & 7) * 16;
        const long node = cand_idx[b * M + spos[cc]];
        const float4* rp = (const float4*)(embed + node * D);
        float4* wp = (float4*)&crows[cc][d0];
#pragma unroll
        for (int j = 0; j < 4; ++j) wp[j] = rp[d0 / 4 + j];
    }
    __syncthreads();

    float acc[SHORT];
#pragma unroll
    for (int cc = 0; cc < SHORT; ++cc) acc[cc] = 0.f;
    const float* W1bot = W1 + (long)D * H;
    for (int d = 0; d < D; ++d) {
        const float w1v = W1bot[d * H + t];
#pragma unroll
        for (int cc = 0; cc < SHORT; ++cc)
            acc[cc] = fmaf(crows[cc][d], w1v, acc[cc]);
    }
    const float qv = qh[b * H + t];
    const float w2 = W2[t];
#pragma unroll
    for (int cc = 0; cc < SHORT; ++cc)
        red[cc][t] = fmaxf(qv + acc[cc], 0.f) * w2;
    __syncthreads();

    if (t < 64) {
#pragma unroll
        for (int cc = 0; cc < SHORT; ++cc) {
            float v = red[cc][t] + red[cc][t + 64];
#pragma unroll
            for (int off = 32; off >= 1; off >>= 1) v += __shfl_xor(v, off);
            if (t == 0) red[cc][0] = v;
        }
    }
    __syncthreads();

    if (t == 0) {
        int k = *topk_ptr;
        if (k > K_MAX) k = K_MAX;
        unsigned used = 0;
        for (int kk = 0; kk < K_MAX; ++kk) {
            if (kk < k) {
                int best = -1, bpos = 0x7fffffff;
                float bv = 0.f;
                for (int cc = 0; cc < SHORT; ++cc) {
                    if (used & (1u << cc)) continue;
                    const float v = red[cc][0];
                    const int p = spos[cc];
                    if (best < 0 || v > bv || (v == bv && p < bpos)) {
                        best = cc; bv = v; bpos = p;
                    }
                }
                used |= 1u << best;
                top_nodes[b * K_MAX + kk] = cand_idx[b * M + bpos];
            } else {
                top_nodes[b * K_MAX + kk] = -1;
            }
        }
    }
}

// ---------------------------------------------------------------------------
// Phase 4: zero the selected rows (after fused copy + refine)
// ---------------------------------------------------------------------------
__global__ void zero_rows_kernel(const int* __restrict__ top_nodes,
                                 float* __restrict__ masked) {
    const int node = top_nodes[blockIdx.x];
    if (node < 0) return;
    masked[(long)node * D + threadIdx.x] = 0.f;
}

// ---------------------------------------------------------------------------
extern "C" void kernel_launch(void* const* d_in, const int* in_sizes, int n_in,
                              void* d_out, int out_size, void* d_ws, size_t ws_size,
                              hipStream_t stream) {
    const float* embed     = (const float*)d_in[0];
    const float* node_feat = (const float*)d_in[1];
    const float* W1        = (const float*)d_in[2];
    const float* b1        = (const float*)d_in[3];
    const float* W2        = (const float*)d_in[4];
    const float* b2        = (const float*)d_in[5];
    const int*   query_idx = (const int*)d_in[6];
    const int*   cand_idx  = (const int*)d_in[7];
    const int*   topk_ptr  = (const int*)d_in[8];

    float* scores = (float*)d_out;                 // B*M
    float* masked = (float*)d_out + (long)BQ * M;  // N*D

    // ws layout
    char* p = (char*)d_ws;
    float*          qh        = (float*)p;          p += (long)BQ * H * 4;
    int*            shortpos  = (int*)p;            p += (long)BQ * SHORT * 4;
    int*            top_nodes = (int*)p;            p += (long)BQ * K_MAX * 4;
    unsigned short* wTswz     = (unsigned short*)p;

    wconv_kernel<<<(H * D) / 256, 256, 0, stream>>>(W1, wTswz);
    qproj_kernel<<<BQ, H, 0, stream>>>(embed, W1, b1, query_idx, qh);

    fused_kernel<<<NTILE + NCOPY, 256, 0, stream>>>(
        embed, wTswz, W2, b2, cand_idx, qh, scores,
        (const f32x4*)node_feat, (f32x4*)masked);

    topk16_kernel<<<BQ, 64, 0, stream>>>(scores, shortpos);
    refine_kernel<<<BQ, 128, 0, stream>>>(embed, W1, W2, qh, cand_idx,
                                          shortpos, topk_ptr, top_nodes);
    zero_rows_kernel<<<BQ * K_MAX, D, 0, stream>>>(top_nodes, masked);
}

// Round 6
// 182.576 us; speedup vs baseline: 2.0632x; 1.1262x over previous
//
#include <hip/hip_runtime.h>
#include <math.h>

#define D 128
#define H 128
#define BQ 1024
#define M 512
#define NNODES 500000
#define K_MAX 8
#define SHORT 16
#define NSCORE BQ                  // one score block per query row (8 m-tiles)
#define NCOPY 2048                 // copy blocks
#define COPY_N4 ((long)NNODES * D / 4)
#define CSTRIDE ((long)NCOPY * 256)

typedef __attribute__((ext_vector_type(8))) short bf16x8;
typedef __attribute__((ext_vector_type(4))) float f32x4;
typedef __attribute__((ext_vector_type(4))) unsigned u32x4;

// RNE fp32->bf16, packed pair
static __device__ __forceinline__ unsigned pack2bf(float a, float b) {
    unsigned ua = __float_as_uint(a);
    unsigned ub = __float_as_uint(b);
    ua = ua + 0x7fffu + ((ua >> 16) & 1u);
    ub = ub + 0x7fffu + ((ub >> 16) & 1u);
    return (ua >> 16) | (ub & 0xffff0000u);
}

// ---------------------------------------------------------------------------
// Phase 0: W1 bottom half -> bf16, h-major, linear image of swizzled LDS tile
// ---------------------------------------------------------------------------
__global__ void wconv_kernel(const float* __restrict__ W1,
                             unsigned short* __restrict__ wTswz) {
    const int idx = blockIdx.x * 256 + threadIdx.x;  // 0..16383
    const int h = idx >> 7;
    const int inner = (idx & 127) * 2;
    const int k = (inner ^ ((h & 7) << 4)) >> 1;
    const float v = W1[(long)(D + k) * H + h];
    wTswz[idx] = (unsigned short)pack2bf(v, 0.f);
}

// ---------------------------------------------------------------------------
// Phase 1: qh[b][h] = b1[h] + embed[query[b]] . W1top   (fp32)
// ---------------------------------------------------------------------------
__global__ void qproj_kernel(const float* __restrict__ embed,
                             const float* __restrict__ W1,
                             const float* __restrict__ b1,
                             const int* __restrict__ query_idx,
                             float* __restrict__ qh) {
    __shared__ float qrow[D];
    const int b = blockIdx.x;
    const int t = threadIdx.x;
    const long qi = query_idx[b];
    qrow[t] = embed[qi * D + t];
    __syncthreads();
    float acc = b1[t];
#pragma unroll 8
    for (int d = 0; d < D; ++d)
        acc = fmaf(qrow[d], W1[d * H + t], acc);
    qh[b * H + t] = acc;
}

// ---------------------------------------------------------------------------
// Phase 2 (FUSED): score rows + node_feat copy, one heterogeneous launch.
//   bid % 3 == 1 -> score block (1024): one query row b, 8 m-tiles,
//                   A gathered DIRECT to registers (no LDS, no barrier),
//                   B staged once in swizzled LDS, software-pipelined.
//   else         -> copy block (2048): 4x-unrolled nontemporal stream.
// ---------------------------------------------------------------------------
__global__ __launch_bounds__(256, 4)
void fused_kernel(const float* __restrict__ embed,
                  const unsigned short* __restrict__ wTswz,
                  const float* __restrict__ W2,
                  const float* __restrict__ b2,
                  const int* __restrict__ cand_idx,
                  const float* __restrict__ qh,
                  float* __restrict__ scores,
                  const f32x4* __restrict__ nf_src,
                  f32x4* __restrict__ nf_dst) {
    __shared__ __align__(16) char Bs[32768];   // [h][k] bf16, swizzled
    const int bid = blockIdx.x;
    const int t   = threadIdx.x;
    const int r3  = bid % 3;

    if (r3 != 1) {
        // ---------------- copy block: nontemporal streaming, 4x unroll -----
        const int cid = (bid / 3) * 2 + (r3 >> 1);    // 0..NCOPY-1
        long i = (long)cid * 256 + t;
        for (; i + 3 * CSTRIDE < COPY_N4; i += 4 * CSTRIDE) {
            const f32x4 v0 = __builtin_nontemporal_load(&nf_src[i]);
            const f32x4 v1 = __builtin_nontemporal_load(&nf_src[i + CSTRIDE]);
            const f32x4 v2 = __builtin_nontemporal_load(&nf_src[i + 2 * CSTRIDE]);
            const f32x4 v3 = __builtin_nontemporal_load(&nf_src[i + 3 * CSTRIDE]);
            __builtin_nontemporal_store(v0, &nf_dst[i]);
            __builtin_nontemporal_store(v1, &nf_dst[i + CSTRIDE]);
            __builtin_nontemporal_store(v2, &nf_dst[i + 2 * CSTRIDE]);
            __builtin_nontemporal_store(v3, &nf_dst[i + 3 * CSTRIDE]);
        }
        for (; i < COPY_N4; i += CSTRIDE) {
            const f32x4 v = __builtin_nontemporal_load(&nf_src[i]);
            __builtin_nontemporal_store(v, &nf_dst[i]);
        }
        return;
    }

    // ------------------- score block: row b, 8 m-tiles ---------------------
    const int b = bid / 3;               // 0..BQ-1

    {   // stage B once: linear copy of pre-swizzled bf16 W1bot (32 KB)
#pragma unroll
        for (int i = 0; i < 8; ++i) {
            const int c = i * 256 + t;
            const uint4 v = ((const uint4*)wTswz)[c];
            *(uint4*)(Bs + (size_t)c * 16) = v;
        }
    }

    const int lane = t & 63;
    const int w    = t >> 6;       // wave id = edge band within tile
    const int g    = lane >> 4;    // k-group
    const int c    = lane & 15;    // row (edge) / col (h) within band
    const int sw   = (c & 7) << 4;

    // hoist per-row operands: qh and W2 at h = cb*16+c
    float qv[8], w2[8];
#pragma unroll
    for (int cb = 0; cb < 8; ++cb) {
        qv[cb] = qh[b * H + cb * 16 + c];
        w2[cb] = W2[cb * 16 + c];
    }
    const float b2v = b2[0];

    // per-lane candidate indices for all 8 tiles (4 g-lanes share a value)
    int idx[8];
    const int ibase = b * M + w * 16 + c;
#pragma unroll
    for (int mt = 0; mt < 8; ++mt) idx[mt] = cand_idx[ibase + mt * 64];

    __syncthreads();   // Bs ready

    // prefetch tile 0 gathers: lane reads k = ks*32 + g*8 .. +8 of its row
    f32x4 buf[8];
    {
        const float* rp = embed + (long)idx[0] * D + g * 8;
#pragma unroll
        for (int ks = 0; ks < 4; ++ks) {
            buf[2 * ks]     = *(const f32x4*)(rp + ks * 32);
            buf[2 * ks + 1] = *(const f32x4*)(rp + ks * 32 + 4);
        }
    }

#pragma unroll
    for (int mt = 0; mt < 8; ++mt) {
        // pack current gathers -> A fragments
        bf16x8 afr[4];
#pragma unroll
        for (int ks = 0; ks < 4; ++ks) {
            u32x4 u;
            u.x = pack2bf(buf[2 * ks].x, buf[2 * ks].y);
            u.y = pack2bf(buf[2 * ks].z, buf[2 * ks].w);
            u.z = pack2bf(buf[2 * ks + 1].x, buf[2 * ks + 1].y);
            u.w = pack2bf(buf[2 * ks + 1].z, buf[2 * ks + 1].w);
            afr[ks] = __builtin_bit_cast(bf16x8, u);
        }
        // prefetch next tile under this tile's MFMA + epilogue
        if (mt < 7) {
            const float* rp = embed + (long)idx[mt + 1] * D + g * 8;
#pragma unroll
            for (int ks = 0; ks < 4; ++ks) {
                buf[2 * ks]     = *(const f32x4*)(rp + ks * 32);
                buf[2 * ks + 1] = *(const f32x4*)(rp + ks * 32 + 4);
            }
        }

        f32x4 acc[8];
#pragma unroll
        for (int cb = 0; cb < 8; ++cb) acc[cb] = (f32x4){0.f, 0.f, 0.f, 0.f};
#pragma unroll
        for (int ks = 0; ks < 4; ++ks) {
            const int koff = (ks * 64 + g * 16) ^ sw;
#pragma unroll
            for (int cb = 0; cb < 8; ++cb) {
                const bf16x8 bv = *(const bf16x8*)(Bs + ((cb * 16 + c) << 8) + koff);
                acc[cb] = __builtin_amdgcn_mfma_f32_16x16x32_bf16(afr[ks], bv, acc[cb], 0, 0, 0);
            }
        }

        // epilogue: relu(qh + acc) . W2 ; butterfly-reduce over 16 c-lanes
        float s0 = 0.f, s1 = 0.f, s2 = 0.f, s3 = 0.f;
#pragma unroll
        for (int cb = 0; cb < 8; ++cb) {
            s0 = fmaf(fmaxf(qv[cb] + acc[cb][0], 0.f), w2[cb], s0);
            s1 = fmaf(fmaxf(qv[cb] + acc[cb][1], 0.f), w2[cb], s1);
            s2 = fmaf(fmaxf(qv[cb] + acc[cb][2], 0.f), w2[cb], s2);
            s3 = fmaf(fmaxf(qv[cb] + acc[cb][3], 0.f), w2[cb], s3);
        }
#pragma unroll
        for (int off = 1; off <= 8; off <<= 1) {
            s0 += __shfl_xor(s0, off);
            s1 += __shfl_xor(s1, off);
            s2 += __shfl_xor(s2, off);
            s3 += __shfl_xor(s3, off);
        }
        if (c == 0) {
            float* out = scores + b * M + mt * 64 + w * 16 + g * 4;
            out[0] = s0 + b2v;
            out[1] = s1 + b2v;
            out[2] = s2 + b2v;
            out[3] = s3 + b2v;
        }
    }
}

// ---------------------------------------------------------------------------
// Phase 3a: approximate top-16 shortlist positions per row (1 wave/row)
// ---------------------------------------------------------------------------
__global__ void topk16_kernel(const float* __restrict__ scores,
                              int* __restrict__ shortpos) {
    const int b = blockIdx.x;
    const int lane = threadIdx.x;
    const float* row = scores + b * M;
    float v[8];
    {
        const float4 x0 = ((const float4*)row)[lane * 2];
        const float4 x1 = ((const float4*)row)[lane * 2 + 1];
        v[0] = x0.x; v[1] = x0.y; v[2] = x0.z; v[3] = x0.w;
        v[4] = x1.x; v[5] = x1.y; v[6] = x1.z; v[7] = x1.w;
    }
    for (int kk = 0; kk < SHORT; ++kk) {
        float bv = v[0];
        int bi = lane * 8;
#pragma unroll
        for (int j = 1; j < 8; ++j)
            if (v[j] > bv) { bv = v[j]; bi = lane * 8 + j; }
#pragma unroll
        for (int off = 32; off >= 1; off >>= 1) {
            const float ov = __shfl_xor(bv, off);
            const int   oi = __shfl_xor(bi, off);
            if (ov > bv || (ov == bv && oi < bi)) { bv = ov; bi = oi; }
        }
        if (lane == 0) shortpos[b * SHORT + kk] = bi;
        if ((bi >> 3) == lane) v[bi & 7] = -3.402823466e38f;
    }
}

// ---------------------------------------------------------------------------
// Phase 3b: exact fp32 rescore of shortlist, top-k with lax.top_k semantics
// ---------------------------------------------------------------------------
__global__ __launch_bounds__(128)
void refine_kernel(const float* __restrict__ embed,
                   const float* __restrict__ W1,
                   const float* __restrict__ W2,
                   const float* __restrict__ qh,
                   const int* __restrict__ cand_idx,
                   const int* __restrict__ shortpos,
                   const int* __restrict__ topk_ptr,
                   int* __restrict__ top_nodes) {
    __shared__ float crows[SHORT][D];
    __shared__ float red[SHORT][D];
    __shared__ int spos[SHORT];
    const int b = blockIdx.x;
    const int t = threadIdx.x;

    if (t < SHORT) spos[t] = shortpos[b * SHORT + t];
    __syncthreads();
    {
        const int cc = t >> 3;
        const int d0 = (t & 7) * 16;
        const long node = cand_idx[b * M + spos[cc]];
        const float4* rp = (const float4*)(embed + node * D);
        float4* wp = (float4*)&crows[cc][d0];
#pragma unroll
        for (int j = 0; j < 4; ++j) wp[j] = rp[d0 / 4 + j];
    }
    __syncthreads();

    float acc[SHORT];
#pragma unroll
    for (int cc = 0; cc < SHORT; ++cc) acc[cc] = 0.f;
    const float* W1bot = W1 + (long)D * H;
    for (int d = 0; d < D; ++d) {
        const float w1v = W1bot[d * H + t];
#pragma unroll
        for (int cc = 0; cc < SHORT; ++cc)
            acc[cc] = fmaf(crows[cc][d], w1v, acc[cc]);
    }
    const float qv = qh[b * H + t];
    const float w2 = W2[t];
#pragma unroll
    for (int cc = 0; cc < SHORT; ++cc)
        red[cc][t] = fmaxf(qv + acc[cc], 0.f) * w2;
    __syncthreads();

    if (t < 64) {
#pragma unroll
        for (int cc = 0; cc < SHORT; ++cc) {
            float v = red[cc][t] + red[cc][t + 64];
#pragma unroll
            for (int off = 32; off >= 1; off >>= 1) v += __shfl_xor(v, off);
            if (t == 0) red[cc][0] = v;
        }
    }
    __syncthreads();

    if (t == 0) {
        int k = *topk_ptr;
        if (k > K_MAX) k = K_MAX;
        unsigned used = 0;
        for (int kk = 0; kk < K_MAX; ++kk) {
            if (kk < k) {
                int best = -1, bpos = 0x7fffffff;
                float bv = 0.f;
                for (int cc = 0; cc < SHORT; ++cc) {
                    if (used & (1u << cc)) continue;
                    const float v = red[cc][0];
                    const int p = spos[cc];
                    if (best < 0 || v > bv || (v == bv && p < bpos)) {
                        best = cc; bv = v; bpos = p;
                    }
                }
                used |= 1u << best;
                top_nodes[b * K_MAX + kk] = cand_idx[b * M + bpos];
            } else {
                top_nodes[b * K_MAX + kk] = -1;
            }
        }
    }
}

// ---------------------------------------------------------------------------
// Phase 4: zero the selected rows (after fused copy + refine)
// ---------------------------------------------------------------------------
__global__ void zero_rows_kernel(const int* __restrict__ top_nodes,
                                 float* __restrict__ masked) {
    const int node = top_nodes[blockIdx.x];
    if (node < 0) return;
    masked[(long)node * D + threadIdx.x] = 0.f;
}

// ---------------------------------------------------------------------------
extern "C" void kernel_launch(void* const* d_in, const int* in_sizes, int n_in,
                              void* d_out, int out_size, void* d_ws, size_t ws_size,
                              hipStream_t stream) {
    const float* embed     = (const float*)d_in[0];
    const float* node_feat = (const float*)d_in[1];
    const float* W1        = (const float*)d_in[2];
    const float* b1        = (const float*)d_in[3];
    const float* W2        = (const float*)d_in[4];
    const float* b2        = (const float*)d_in[5];
    const int*   query_idx = (const int*)d_in[6];
    const int*   cand_idx  = (const int*)d_in[7];
    const int*   topk_ptr  = (const int*)d_in[8];

    float* scores = (float*)d_out;                 // B*M
    float* masked = (float*)d_out + (long)BQ * M;  // N*D

    // ws layout
    char* p = (char*)d_ws;
    float*          qh        = (float*)p;          p += (long)BQ * H * 4;
    int*            shortpos  = (int*)p;            p += (long)BQ * SHORT * 4;
    int*            top_nodes = (int*)p;            p += (long)BQ * K_MAX * 4;
    unsigned short* wTswz     = (unsigned short*)p;

    wconv_kernel<<<(H * D) / 256, 256, 0, stream>>>(W1, wTswz);
    qproj_kernel<<<BQ, H, 0, stream>>>(embed, W1, b1, query_idx, qh);

    fused_kernel<<<NSCORE + NCOPY, 256, 0, stream>>>(
        embed, wTswz, W2, b2, cand_idx, qh, scores,
        (const f32x4*)node_feat, (f32x4*)masked);

    topk16_kernel<<<BQ, 64, 0, stream>>>(scores, shortpos);
    refine_kernel<<<BQ, 128, 0, stream>>>(embed, W1, W2, qh, cand_idx,
                                          shortpos, topk_ptr, top_nodes);
    zero_rows_kernel<<<BQ * K_MAX, D, 0, stream>>>(top_nodes, masked);
}